// Round 12
// baseline (1160.949 us; speedup 1.0000x reference)
//
#include <hip/hip_runtime.h>
#include <hip/hip_bf16.h>

typedef unsigned short u16;
typedef __attribute__((ext_vector_type(8))) short short8;
typedef __attribute__((ext_vector_type(4))) float f32x4;

#define DIM 2048
#define HID 1408
#define NE 16
#define NTOK 2048
#define TOPK_ 4
#define SHID 2816
#define CAPROWS 10240
#define MAXTILES (CAPROWS / 128)   // 80; 80 % 8 == 0 so XCD == slot % 8
#define AUX_IDX (2048 * 2048)

__device__ inline u16 f2bf(float f) {
  __bf16 h = (__bf16)f;                 // RNE hardware convert
  return __builtin_bit_cast(u16, h);
}

__device__ inline void gload_lds16(const void* g, void* l) {
  __builtin_amdgcn_global_load_lds(
      (const __attribute__((address_space(1))) unsigned int*)g,
      (__attribute__((address_space(3))) unsigned int*)l, 16, 0, 0);
}

// ---------------- gate phase 1: f64 logits, no atomics ----------------
__global__ __launch_bounds__(256) void gate_dots_kernel(
    const float* __restrict__ x, const float* __restrict__ gw,
    double* __restrict__ logits) {
  int t = blockIdx.x;
  const float* xt = x + (size_t)t * DIM;
  __shared__ double red[NE][4];
  int lane = threadIdx.x & 63, wid = threadIdx.x >> 6;
  for (int e = 0; e < NE; ++e) {
    const float* w = gw + e * DIM;
    double p = 0.0;
    for (int d = threadIdx.x; d < DIM; d += 256)
      p += (double)xt[d] * (double)w[d];
#pragma unroll
    for (int s = 32; s; s >>= 1) p += __shfl_xor(p, s);
    if (lane == 0) red[e][wid] = p;
  }
  __syncthreads();
  if (threadIdx.x < NE) {
    int e = threadIdx.x;
    logits[(size_t)t * NE + e] = red[e][0] + red[e][1] + red[e][2] + red[e][3];
  }
}

// ---------------- gate phase 2: per-token softmax + top-4 ----------------
__global__ __launch_bounds__(256) void topk_kernel(
    const double* __restrict__ logits,
    int* __restrict__ idxb, float* __restrict__ wtb,
    int* __restrict__ counts, float* __restrict__ ssum) {
  __shared__ int lcnt[NE];
  __shared__ float lsum[NE];
  if (threadIdx.x < NE) { lcnt[threadIdx.x] = 0; lsum[threadIdx.x] = 0.f; }
  __syncthreads();
  int t = blockIdx.x * 256 + threadIdx.x;
  int lane = threadIdx.x & 63;
  double sc[NE];
  double m = -1e300;
#pragma unroll
  for (int e = 0; e < NE; ++e) {
    sc[e] = logits[(size_t)t * NE + e];
    if (sc[e] > m) m = sc[e];
  }
  double s = 0.0;
#pragma unroll
  for (int e = 0; e < NE; ++e) { sc[e] = exp(sc[e] - m); s += sc[e]; }
  double inv = 1.0 / s;
#pragma unroll
  for (int e = 0; e < NE; ++e) sc[e] *= inv;
  unsigned used = 0;
  for (int k = 0; k < TOPK_; ++k) {
    int be = 0; double bv = -1.0;
#pragma unroll
    for (int e = 0; e < NE; ++e)
      if (!((used >> e) & 1u) && sc[e] > bv) { bv = sc[e]; be = e; }
    used |= 1u << be;
    idxb[t * TOPK_ + k] = be;
    wtb[t * TOPK_ + k] = (float)bv;     // ROUTE_SCALE = 1
    atomicAdd(&lcnt[be], 1);
  }
#pragma unroll
  for (int e = 0; e < NE; ++e) {
    float v = (float)sc[e];
#pragma unroll
    for (int sft = 32; sft; sft >>= 1) v += __shfl_xor(v, sft);
    if (lane == 0) atomicAdd(&lsum[e], v);
  }
  __syncthreads();
  if (threadIdx.x < NE) {
    atomicAdd(&counts[threadIdx.x], lcnt[threadIdx.x]);
    atomicAdd(&ssum[threadIdx.x], lsum[threadIdx.x]);
  }
}

// -------- segment offsets (128-padded), XCD-grouped tile map, aux loss --------
__global__ __launch_bounds__(256) void setup_kernel(
    const int* __restrict__ counts, int* __restrict__ off, int* __restrict__ cap,
    const float* __restrict__ ssum, int* __restrict__ perm, float* __restrict__ pwt,
    float* __restrict__ aux_out,
    int* __restrict__ tile2e, int* __restrict__ tile2m0) {
  for (int i = threadIdx.x; i < MAXTILES; i += 256) tile2e[i] = -1;
  __syncthreads();
  if (threadIdx.x == 0) {
    int o = 0; double aux = 0.0; int nt = 0;
    for (int e = 0; e < NE; ++e) {
      off[e] = o;
      int c = (counts[e] + 127) & ~127;
      cap[e] = c;
      for (int t = 0; t < (c >> 7); ++t) {
        int slot = (nt / 10) + (nt % 10) * 8;
        tile2e[slot] = e;
        tile2m0[slot] = o + t * 128;
        ++nt;
      }
      o += c;
      aux += ((double)counts[e] / (NTOK * TOPK_)) * ((double)ssum[e] / NTOK);
    }
    aux_out[0] = (float)(NE * aux);
  }
  for (int i = threadIdx.x; i < CAPROWS; i += 256) { perm[i] = 0; pwt[i] = 0.f; }
}

__global__ __launch_bounds__(256) void scatter_kernel(
    const int* __restrict__ idxb, const float* __restrict__ wtb,
    const int* __restrict__ off, int* __restrict__ cursor,
    int* __restrict__ perm, float* __restrict__ pwt) {
  int t = blockIdx.x * 256 + threadIdx.x;
  if (t >= NTOK) return;
  for (int k = 0; k < TOPK_; ++k) {
    int e = idxb[t * TOPK_ + k];
    int s = atomicAdd(&cursor[e], 1);
    int p = off[e] + s;
    perm[p] = t;
    pwt[p] = wtb[t * TOPK_ + k];
  }
}

// ---------------- f32 -> bf16 stream convert (x only) ----------------
__global__ __launch_bounds__(256) void cvtN_kernel(const float* __restrict__ in,
                                                   u16* __restrict__ out, long n) {
  long stride = (long)gridDim.x * 2048;
  for (long i = ((long)blockIdx.x * 256 + threadIdx.x) * 8; i < n; i += stride) {
    float4 a = *(const float4*)(in + i);
    float4 b = *(const float4*)(in + i + 4);
    union { u16 u[8]; uint4 v; } o;
    o.u[0] = f2bf(a.x); o.u[1] = f2bf(a.y); o.u[2] = f2bf(a.z); o.u[3] = f2bf(a.w);
    o.u[4] = f2bf(b.x); o.u[5] = f2bf(b.y); o.u[6] = f2bf(b.z); o.u[7] = f2bf(b.w);
    *(uint4*)(out + i) = o.v;
  }
}

// ====== GEMM v10 (flatmm-style): A via LDS, B DIRECT global->reg->MFMA ======
// BM=128, BN=64/matrix, BK=64. A: bf16 gload_lds dbuf 2x16KB (32KB LDS total),
// source pre-swizzled chunk^=(row&7); conflicts measured 0.
// B: each lane loads ITS OWN fragment data straight from global f32 (2 x float4
// per 8-elem fragment), one iter ahead (single reg buffer), cvt->bf16 at use.
// No B LDS: no ds_write/ds_read/lgkmcnt for B; 1 barrier/iter protects A only.
// vmcnt derivation: per iter issue stageA(t+1)=4 (older) then loadB(t+1)=16
//   -> vmcnt(16) drains exactly A(t+1); B(t+1) stays in flight across barrier.
// Compiler auto-waits B(t) at first use inside compute (its own loads).
template <bool GATHER, bool DUAL, int EPI>
__global__ __launch_bounds__(256) void gemm10_kernel(
    const u16* __restrict__ A, int lda,
    const float* __restrict__ B1, const float* __restrict__ B3,
    int ldb, long bstride, int K,
    const int* __restrict__ tile2e, const int* __restrict__ tile2m0,
    const int* __restrict__ seg_off, const int* __restrict__ seg_cnt,
    const int* __restrict__ perm, const float* __restrict__ pwt,
    float* __restrict__ C0, int ldc0,
    u16* __restrict__ Cb, int ldcb, int Mfixed) {
  int e, m0, rowlim;
  if (tile2e) {
    e = tile2e[blockIdx.x];
    if (e < 0) return;
    m0 = tile2m0[blockIdx.x];
    rowlim = seg_off[e] + seg_cnt[e];
  } else {
    e = 0;
    m0 = blockIdx.x * 128;
    if (m0 >= Mfixed) return;
    rowlim = Mfixed;
  }
  int n0 = blockIdx.y * 64;
  const float* Bb1 = B1 + (long)e * bstride;
  const float* Bb3 = DUAL ? (B3 + (long)e * bstride) : nullptr;

  __shared__ u16 As[2][128 * 64];               // 2 x 16 KB; ONLY LDS use

  int tid = threadIdx.x;
  int lane = tid & 63;
  int wid = tid >> 6;
  int wr = wid >> 1, wc = wid & 1;

  f32x4 acc1[4][2], acc3[4][2];
#pragma unroll
  for (int mi = 0; mi < 4; ++mi)
#pragma unroll
    for (int ni = 0; ni < 2; ++ni) {
      acc1[mi][ni] = (f32x4){0.f, 0.f, 0.f, 0.f};
      acc3[mi][ni] = (f32x4){0.f, 0.f, 0.f, 0.f};
    }

  // ---- A staging: row=tid>>3 (+32/it), chunk=tid&7; SOURCE chunk XOR'd (rule #21) ----
  int sr = tid >> 3;
  int scA = tid & 7;
  long abase[4];
#pragma unroll
  for (int it = 0; it < 4; ++it) {
    int row = m0 + it * 32 + sr;
    int rid = GATHER ? perm[row] : row;
    abase[it] = (long)rid * lda + ((scA ^ (sr & 7)) << 3);
  }
  // ---- B fragment addressing: lane owns row n0+wc*32+ni*16+(lane&15),
  //      k-chunk base (lane>>4)*8 within each 32-wide kk slice ----
  long brow[2];
#pragma unroll
  for (int ni = 0; ni < 2; ++ni)
    brow[ni] = (long)(n0 + wc * 32 + ni * 16 + (lane & 15)) * ldb + ((lane >> 4) << 3);

  // B reg buffer: [ni][kk-half][float4-half]
  f32x4 Br1[2][2][2], Br3[2][2][2];

  auto stageA = [&](int buf, int k0) {
#pragma unroll
    for (int it = 0; it < 4; ++it)
      gload_lds16(A + abase[it] + k0, &As[buf][(it * 32 + sr) * 64 + scA * 8]);
  };
  auto loadB = [&](int k0) {
#pragma unroll
    for (int ni = 0; ni < 2; ++ni)
#pragma unroll
      for (int kx = 0; kx < 2; ++kx)
#pragma unroll
        for (int h = 0; h < 2; ++h) {
          Br1[ni][kx][h] = *(const f32x4*)(Bb1 + brow[ni] + k0 + kx * 32 + h * 4);
          if (DUAL)
            Br3[ni][kx][h] = *(const f32x4*)(Bb3 + brow[ni] + k0 + kx * 32 + h * 4);
        }
  };
  auto cvt8 = [&](const f32x4& lo, const f32x4& hi) {
    short8 f;
    f[0] = (short)f2bf(lo[0]); f[1] = (short)f2bf(lo[1]);
    f[2] = (short)f2bf(lo[2]); f[3] = (short)f2bf(lo[3]);
    f[4] = (short)f2bf(hi[0]); f[5] = (short)f2bf(hi[1]);
    f[6] = (short)f2bf(hi[2]); f[7] = (short)f2bf(hi[3]);
    return f;
  };
  auto compute = [&](int cur) {
#pragma unroll
    for (int kx = 0; kx < 2; ++kx) {
      int kk = kx * 32;
      short8 af[4], b1f[2], b3f[2];
#pragma unroll
      for (int i = 0; i < 4; ++i) {
        int R = wr * 64 + i * 16 + (lane & 15);
        int c = (kk >> 3) + (lane >> 4);
        af[i] = *(const short8*)&As[cur][R * 64 + ((c ^ (R & 7)) << 3)];
      }
#pragma unroll
      for (int ni = 0; ni < 2; ++ni) {
        b1f[ni] = cvt8(Br1[ni][kx][0], Br1[ni][kx][1]);
        if (DUAL) b3f[ni] = cvt8(Br3[ni][kx][0], Br3[ni][kx][1]);
      }
#pragma unroll
      for (int mi = 0; mi < 4; ++mi)
#pragma unroll
        for (int ni = 0; ni < 2; ++ni) {
          acc1[mi][ni] = __builtin_amdgcn_mfma_f32_16x16x32_bf16(af[mi], b1f[ni], acc1[mi][ni], 0, 0, 0);
          if (DUAL)
            acc3[mi][ni] = __builtin_amdgcn_mfma_f32_16x16x32_bf16(af[mi], b3f[ni], acc3[mi][ni], 0, 0, 0);
        }
    }
  };

  // prologue: B(0) + A(0), full drain
  loadB(0);
  stageA(0, 0);
  asm volatile("s_waitcnt vmcnt(0)" ::: "memory");
  __builtin_amdgcn_sched_barrier(0);
  __builtin_amdgcn_s_barrier();
  __builtin_amdgcn_sched_barrier(0);

  int NT = K >> 6;
  int cur = 0;
  for (int t = 0; t < NT; ++t) {
    int nxt = cur ^ 1;
    bool pf = (t + 1 < NT);
    if (pf) stageA(nxt, (t + 1) << 6);     // 4 vm, hides under compute
    compute(cur);                           // consumes B(t) regs (compiler waits vmcnt(4))
    if (pf) {
      loadB((t + 1) << 6);                  // 16 vm into freed B regs
      __builtin_amdgcn_sched_barrier(0);
      asm volatile("s_waitcnt vmcnt(16)" ::: "memory");   // drain A(t+1) only
      __builtin_amdgcn_sched_barrier(0);
      __builtin_amdgcn_s_barrier();         // publish As[nxt]
      __builtin_amdgcn_sched_barrier(0);
    }
    cur = nxt;
  }

  int rbase = m0 + wr * 64 + (lane >> 4) * 4;
  int cbase = n0 + wc * 32 + (lane & 15);
#pragma unroll
  for (int mi = 0; mi < 4; ++mi) {
#pragma unroll
    for (int ni = 0; ni < 2; ++ni) {
      int col = cbase + ni * 16;
#pragma unroll
      for (int r = 0; r < 4; ++r) {
        int row = rbase + mi * 16 + r;
        float v = acc1[mi][ni][r];
        if (EPI == 0) {
          float a3 = acc3[mi][ni][r];
          float sg = v / (1.f + __expf(-v));
          Cb[(long)row * ldcb + col] = f2bf(sg * a3);
        } else if (EPI == 1) {
          C0[(long)row * ldc0 + col] = v;
        } else {
          if (row < rowlim) {
            atomicAdd(&C0[(long)perm[row] * ldc0 + col], v * pwt[row]);
          }
        }
      }
    }
  }
}

extern "C" void kernel_launch(void* const* d_in, const int* in_sizes, int n_in,
                              void* d_out, int out_size, void* d_ws, size_t ws_size,
                              hipStream_t stream) {
  (void)in_sizes; (void)n_in; (void)out_size; (void)ws_size;
  const float* x   = (const float*)d_in[0];
  const float* gw  = (const float*)d_in[1];
  const float* w1  = (const float*)d_in[2];
  const float* w2  = (const float*)d_in[3];
  const float* w3  = (const float*)d_in[4];
  const float* sw1 = (const float*)d_in[5];
  const float* sw2 = (const float*)d_in[6];
  const float* sw3 = (const float*)d_in[7];
  float* out = (float*)d_out;
  char* ws = (char*)d_ws;

  int*   counts = (int*)(ws + 0);
  int*   cursor = (int*)(ws + 64);
  int*   off    = (int*)(ws + 128);
  int*   cap    = (int*)(ws + 192);
  float* ssum   = (float*)(ws + 256);
  int*   tile2e = (int*)(ws + 1024);
  int*   tile2m0= (int*)(ws + 2048);
  int*   idxb   = (int*)(ws + 4096);
  float* wtb    = (float*)(ws + 4096 + 32768);
  int*   perm   = (int*)(ws + 4096 + 65536);
  float* pwt    = (float*)(ws + 4096 + 65536 + 40960);
  u16*   xb     = (u16*)(ws + 262144);                 // 2048x2048 bf16
  double* logits = (double*)(ws + 8650752);            // 2048x16 f64
  u16*   hbuf   = (u16*)(ws + 16777216);               // 10240x1408 bf16
  u16*   hsb    = (u16*)(ws + 45613056);               // 2048x2816 bf16

  hipMemsetAsync(ws, 0, 512, stream);
  gate_dots_kernel<<<dim3(NTOK), dim3(256), 0, stream>>>(x, gw, logits);
  topk_kernel<<<dim3(NTOK / 256), dim3(256), 0, stream>>>(logits, idxb, wtb, counts, ssum);
  setup_kernel<<<dim3(1), dim3(256), 0, stream>>>(counts, off, cap, ssum, perm, pwt,
                                                  out + AUX_IDX, tile2e, tile2m0);
  scatter_kernel<<<dim3(8), dim3(256), 0, stream>>>(idxb, wtb, off, cursor, perm, pwt);
  cvtN_kernel<<<dim3(2048), dim3(256), 0, stream>>>(x, xb, (long)NTOK * DIM);

  // routed h = silu(gather(x)@w1^T) * (gather(x)@w3^T) -> bf16
  gemm10_kernel<true, true, 0><<<dim3(MAXTILES, HID / 64), dim3(256), 0, stream>>>(
      xb, DIM, w1, w3, DIM, (long)HID * DIM, DIM, tile2e, tile2m0,
      off, counts, perm, pwt, nullptr, 0, hbuf, HID, 0);
  // shared hs = silu(x@sw1^T) * (x@sw3^T) -> bf16
  gemm10_kernel<false, true, 0><<<dim3(NTOK / 128, SHID / 64), dim3(256), 0, stream>>>(
      xb, DIM, sw1, sw3, DIM, 0, DIM, nullptr, nullptr,
      nullptr, nullptr, nullptr, nullptr, nullptr, 0, hsb, SHID, NTOK);
  // z = hs @ sw2^T  (plain f32 store into out)
  gemm10_kernel<false, false, 1><<<dim3(NTOK / 128, DIM / 64), dim3(256), 0, stream>>>(
      hsb, SHID, sw2, nullptr, SHID, 0, SHID, nullptr, nullptr,
      nullptr, nullptr, nullptr, nullptr, out, DIM, nullptr, 0, NTOK);
  // out += (h @ w2^T) * pwt   (atomic accumulate on top of z)
  gemm10_kernel<false, false, 2><<<dim3(MAXTILES, DIM / 64), dim3(256), 0, stream>>>(
      hbuf, HID, w2, nullptr, HID, (long)DIM * HID, HID, tile2e, tile2m0,
      off, counts, perm, pwt, out, DIM, nullptr, 0, 0);
}

// Round 13
// 726.612 us; speedup vs baseline: 1.5978x; 1.5978x over previous
//
#include <hip/hip_runtime.h>
#include <hip/hip_bf16.h>

typedef unsigned short u16;
typedef __attribute__((ext_vector_type(8))) short short8;
typedef __attribute__((ext_vector_type(4))) float f32x4;

#define DIM 2048
#define HID 1408
#define NE 16
#define NTOK 2048
#define TOPK_ 4
#define SHID 2816
#define CAPROWS 10240
#define MAXTILES (CAPROWS / 128)   // 80; 80 % 8 == 0 so XCD == slot % 8
#define AUX_IDX (2048 * 2048)
#define NW13 46137344L             // NE*HID*DIM elems per routed weight matrix
#define NX 4194304L                // NTOK*DIM

__device__ inline u16 f2bf(float f) {
  __bf16 h = (__bf16)f;                 // RNE hardware convert
  return __builtin_bit_cast(u16, h);
}

__device__ inline void gload_lds16(const void* g, void* l) {
  __builtin_amdgcn_global_load_lds(
      (const __attribute__((address_space(1))) unsigned int*)g,
      (__attribute__((address_space(3))) unsigned int*)l, 16, 0, 0);
}

__device__ inline void cvt8_store(const float* __restrict__ in, u16* __restrict__ out, long i) {
  float4 a = *(const float4*)(in + i);
  float4 b = *(const float4*)(in + i + 4);
  union { u16 u[8]; uint4 v; } o;
  o.u[0] = f2bf(a.x); o.u[1] = f2bf(a.y); o.u[2] = f2bf(a.z); o.u[3] = f2bf(a.w);
  o.u[4] = f2bf(b.x); o.u[5] = f2bf(b.y); o.u[6] = f2bf(b.z); o.u[7] = f2bf(b.w);
  *(uint4*)(out + i) = o.v;
}

// ---- prep: gate f64 logits (blocks 0..2047)  ||  cvt w1,w3,x -> bf16 (blocks 2048+) ----
__global__ __launch_bounds__(256) void prep_kernel(
    const float* __restrict__ x, const float* __restrict__ gw,
    double* __restrict__ logits,
    const float* __restrict__ w1, const float* __restrict__ w3,
    u16* __restrict__ w1b, u16* __restrict__ w3b, u16* __restrict__ xb) {
  if ((int)blockIdx.x >= NTOK) {
    long i0 = ((long)(blockIdx.x - NTOK) * 256 + threadIdx.x) * 8;
    long stride = (long)(gridDim.x - NTOK) * 2048;
    const long ntot = 2 * NW13 + NX;
    for (long i = i0; i < ntot; i += stride) {
      if (i < NW13)            cvt8_store(w1, w1b, i);
      else if (i < 2 * NW13)   cvt8_store(w3 + (i - NW13) - (i - NW13), w3b, i - NW13), cvt8_store(w3, w3b, i - NW13);
      else                     cvt8_store(x, xb, i - 2 * NW13);
    }
    return;
  }
  int t = blockIdx.x;
  const float* xt = x + (size_t)t * DIM;
  __shared__ double red[NE][4];
  int lane = threadIdx.x & 63, wid = threadIdx.x >> 6;
  for (int e = 0; e < NE; ++e) {
    const float* w = gw + e * DIM;
    double p = 0.0;
    for (int d = threadIdx.x; d < DIM; d += 256)
      p += (double)xt[d] * (double)w[d];
#pragma unroll
    for (int s = 32; s; s >>= 1) p += __shfl_xor(p, s);
    if (lane == 0) red[e][wid] = p;
  }
  __syncthreads();
  if (threadIdx.x < NE)
    logits[(size_t)t * NE + threadIdx.x] =
        red[threadIdx.x][0] + red[threadIdx.x][1] + red[threadIdx.x][2] + red[threadIdx.x][3];
}

// ---------------- gate phase 2: per-token softmax + top-4 ----------------
__global__ __launch_bounds__(256) void topk_kernel(
    const double* __restrict__ logits,
    int* __restrict__ idxb, float* __restrict__ wtb,
    int* __restrict__ counts, float* __restrict__ ssum) {
  __shared__ int lcnt[NE];
  __shared__ float lsum[NE];
  if (threadIdx.x < NE) { lcnt[threadIdx.x] = 0; lsum[threadIdx.x] = 0.f; }
  __syncthreads();
  int t = blockIdx.x * 256 + threadIdx.x;
  int lane = threadIdx.x & 63;
  double sc[NE];
  double m = -1e300;
#pragma unroll
  for (int e = 0; e < NE; ++e) {
    sc[e] = logits[(size_t)t * NE + e];
    if (sc[e] > m) m = sc[e];
  }
  double s = 0.0;
#pragma unroll
  for (int e = 0; e < NE; ++e) { sc[e] = exp(sc[e] - m); s += sc[e]; }
  double inv = 1.0 / s;
#pragma unroll
  for (int e = 0; e < NE; ++e) sc[e] *= inv;
  unsigned used = 0;
  for (int k = 0; k < TOPK_; ++k) {
    int be = 0; double bv = -1.0;
#pragma unroll
    for (int e = 0; e < NE; ++e)
      if (!((used >> e) & 1u) && sc[e] > bv) { bv = sc[e]; be = e; }
    used |= 1u << be;
    idxb[t * TOPK_ + k] = be;
    wtb[t * TOPK_ + k] = (float)bv;     // ROUTE_SCALE = 1
    atomicAdd(&lcnt[be], 1);
  }
#pragma unroll
  for (int e = 0; e < NE; ++e) {
    float v = (float)sc[e];
#pragma unroll
    for (int sft = 32; sft; sft >>= 1) v += __shfl_xor(v, sft);
    if (lane == 0) atomicAdd(&lsum[e], v);
  }
  __syncthreads();
  if (threadIdx.x < NE) {
    atomicAdd(&counts[threadIdx.x], lcnt[threadIdx.x]);
    atomicAdd(&ssum[threadIdx.x], lsum[threadIdx.x]);
  }
}

// -------- segment offsets (128-padded), XCD-grouped tile map, aux loss --------
__global__ __launch_bounds__(256) void setup_kernel(
    const int* __restrict__ counts, int* __restrict__ off, int* __restrict__ cap,
    const float* __restrict__ ssum, int* __restrict__ perm, float* __restrict__ pwt,
    float* __restrict__ aux_out,
    int* __restrict__ tile2e, int* __restrict__ tile2m0) {
  for (int i = threadIdx.x; i < MAXTILES; i += 256) tile2e[i] = -1;
  __syncthreads();
  if (threadIdx.x == 0) {
    int o = 0; double aux = 0.0; int nt = 0;
    for (int e = 0; e < NE; ++e) {
      off[e] = o;
      int c = (counts[e] + 127) & ~127;
      cap[e] = c;
      for (int t = 0; t < (c >> 7); ++t) {
        int slot = (nt / 10) + (nt % 10) * 8;
        tile2e[slot] = e;
        tile2m0[slot] = o + t * 128;
        ++nt;
      }
      o += c;
      aux += ((double)counts[e] / (NTOK * TOPK_)) * ((double)ssum[e] / NTOK);
    }
    aux_out[0] = (float)(NE * aux);
  }
  for (int i = threadIdx.x; i < CAPROWS; i += 256) { perm[i] = 0; pwt[i] = 0.f; }
}

__global__ __launch_bounds__(256) void scatter_kernel(
    const int* __restrict__ idxb, const float* __restrict__ wtb,
    const int* __restrict__ off, int* __restrict__ cursor,
    int* __restrict__ perm, float* __restrict__ pwt) {
  int t = blockIdx.x * 256 + threadIdx.x;
  if (t >= NTOK) return;
  for (int k = 0; k < TOPK_; ++k) {
    int e = idxb[t * TOPK_ + k];
    int s = atomicAdd(&cursor[e], 1);
    int p = off[e] + s;
    perm[p] = t;
    pwt[p] = wtb[t * TOPK_ + k];
  }
}

// ---------------- standalone f32 -> bf16 stream convert (fallback path) ----------------
__global__ __launch_bounds__(256) void cvtN_kernel(const float* __restrict__ in,
                                                   u16* __restrict__ out, long n) {
  long stride = (long)gridDim.x * 2048;
  for (long i = ((long)blockIdx.x * 256 + threadIdx.x) * 8; i < n; i += stride)
    cvt8_store(in, out, i);
}

// ====== GEMM v9 (R10, verified 604): f32 B reg-staged depth-2; + optional fused cvt ======
template <bool GATHER, bool DUAL, int EPI>
__global__ __launch_bounds__(256) void gemm9_kernel(
    const u16* __restrict__ A, int lda,
    const float* __restrict__ B1, const float* __restrict__ B3,
    int ldb, long bstride, int K,
    const int* __restrict__ tile2e, const int* __restrict__ tile2m0,
    const int* __restrict__ seg_off, const int* __restrict__ seg_cnt,
    const int* __restrict__ perm, const float* __restrict__ pwt,
    float* __restrict__ C0, int ldc0,
    u16* __restrict__ Cb, int ldcb, int Mfixed,
    const float* __restrict__ csrc, u16* __restrict__ cdst, long cn, int nxg) {
  if ((int)blockIdx.x >= nxg) {          // fused cvt tail blocks
    long i0 = ((long)((blockIdx.x - nxg) * gridDim.y + blockIdx.y) * 256 + threadIdx.x) * 8;
    long stride = (long)(gridDim.x - nxg) * gridDim.y * 2048;
    for (long i = i0; i < cn; i += stride) cvt8_store(csrc, cdst, i);
    return;
  }
  int e, m0, rowlim;
  if (tile2e) {
    e = tile2e[blockIdx.x];
    if (e < 0) return;
    m0 = tile2m0[blockIdx.x];
    rowlim = seg_off[e] + seg_cnt[e];
  } else {
    e = 0;
    m0 = blockIdx.x * 128;
    if (m0 >= Mfixed) return;
    rowlim = Mfixed;
  }
  int n0 = blockIdx.y * 64;
  const float* Bb1 = B1 + (long)e * bstride;
  const float* Bb3 = DUAL ? (B3 + (long)e * bstride) : nullptr;

  __shared__ u16 As[2][128 * 64];
  __shared__ u16 Bs1[64 * 64];
  __shared__ u16 Bs3[DUAL ? 64 * 64 : 1];

  int tid = threadIdx.x;
  int lane = tid & 63;
  int wid = tid >> 6;
  int wr = wid >> 1, wc = wid & 1;

  f32x4 acc1[4][2], acc3[4][2];
#pragma unroll
  for (int mi = 0; mi < 4; ++mi)
#pragma unroll
    for (int ni = 0; ni < 2; ++ni) {
      acc1[mi][ni] = (f32x4){0.f, 0.f, 0.f, 0.f};
      acc3[mi][ni] = (f32x4){0.f, 0.f, 0.f, 0.f};
    }

  int sr = tid >> 3;
  int scA = tid & 7;
  long abase[4];
#pragma unroll
  for (int it = 0; it < 4; ++it) {
    int row = m0 + it * 32 + sr;
    int rid = GATHER ? perm[row] : row;
    abase[it] = (long)rid * lda + ((scA ^ (sr & 7)) << 3);
  }
  int brr = tid >> 4;
  int gB = tid & 15;
  int wofs = (((gB >> 1) ^ (brr & 7)) << 3) + ((gB & 1) << 2);
  long bbase[4];
#pragma unroll
  for (int it = 0; it < 4; ++it)
    bbase[it] = (long)(n0 + it * 16 + brr) * ldb + gB * 4;

  float4 R1a[4], R3a[4], R1b[4], R3b[4];

  auto stageA = [&](int buf, int k0) {
#pragma unroll
    for (int it = 0; it < 4; ++it)
      gload_lds16(A + abase[it] + k0, &As[buf][(it * 32 + sr) * 64 + scA * 8]);
  };
  auto loadB = [&](float4 (&r1)[4], float4 (&r3)[4], int k0) {
#pragma unroll
    for (int it = 0; it < 4; ++it) r1[it] = *(const float4*)(Bb1 + bbase[it] + k0);
    if (DUAL) {
#pragma unroll
      for (int it = 0; it < 4; ++it) r3[it] = *(const float4*)(Bb3 + bbase[it] + k0);
    }
  };
  auto writeB = [&](float4 (&r1)[4], float4 (&r3)[4]) {
#pragma unroll
    for (int it = 0; it < 4; ++it) {
      int lo = (it * 16 + brr) * 64 + wofs;
      ushort4 o;
      o.x = f2bf(r1[it].x); o.y = f2bf(r1[it].y); o.z = f2bf(r1[it].z); o.w = f2bf(r1[it].w);
      *(ushort4*)&Bs1[lo] = o;
      if (DUAL) {
        ushort4 q;
        q.x = f2bf(r3[it].x); q.y = f2bf(r3[it].y); q.z = f2bf(r3[it].z); q.w = f2bf(r3[it].w);
        *(ushort4*)&Bs3[lo] = q;
      }
    }
  };
  auto compute = [&](int cur) {
#pragma unroll
    for (int kk = 0; kk < 64; kk += 32) {
      short8 af[4], b1f[2], b3f[2];
#pragma unroll
      for (int i = 0; i < 4; ++i) {
        int R = wr * 64 + i * 16 + (lane & 15);
        int c = (kk >> 3) + (lane >> 4);
        af[i] = *(const short8*)&As[cur][R * 64 + ((c ^ (R & 7)) << 3)];
      }
#pragma unroll
      for (int i = 0; i < 2; ++i) {
        int r = wc * 32 + i * 16 + (lane & 15);
        int cR = (kk >> 3) + (lane >> 4);
        b1f[i] = *(const short8*)&Bs1[r * 64 + ((cR ^ (r & 7)) << 3)];
        if (DUAL)
          b3f[i] = *(const short8*)&Bs3[r * 64 + ((cR ^ (r & 7)) << 3)];
      }
#pragma unroll
      for (int mi = 0; mi < 4; ++mi)
#pragma unroll
        for (int ni = 0; ni < 2; ++ni) {
          acc1[mi][ni] = __builtin_amdgcn_mfma_f32_16x16x32_bf16(af[mi], b1f[ni], acc1[mi][ni], 0, 0, 0);
          if (DUAL)
            acc3[mi][ni] = __builtin_amdgcn_mfma_f32_16x16x32_bf16(af[mi], b3f[ni], acc3[mi][ni], 0, 0, 0);
        }
    }
  };

  int NT = K >> 6;
  loadB(R1a, R3a, 0);
  stageA(0, 0);
  loadB(R1b, R3b, 64);

#define GEMM9_STEP(T, CUR, RB1, RB3)                                          \
  {                                                                           \
    int t_ = (T);                                                             \
    writeB(RB1, RB3);                                                         \
    bool hasA = (t_ + 1 < NT), hasB = (t_ + 2 < NT);                          \
    if (hasA) stageA((CUR) ^ 1, (t_ + 1) << 6);                               \
    if (hasB) loadB(RB1, RB3, (t_ + 2) << 6);                                 \
    if (hasB) {                                                               \
      if (DUAL) asm volatile("s_waitcnt vmcnt(20)" ::: "memory");             \
      else      asm volatile("s_waitcnt vmcnt(12)" ::: "memory");             \
    } else if (hasA) {                                                        \
      if (DUAL) asm volatile("s_waitcnt vmcnt(12)" ::: "memory");             \
      else      asm volatile("s_waitcnt vmcnt(8)"  ::: "memory");             \
    } else {                                                                  \
      asm volatile("s_waitcnt vmcnt(0)" ::: "memory");                        \
    }                                                                         \
    asm volatile("s_waitcnt lgkmcnt(0)" ::: "memory");                        \
    __builtin_amdgcn_sched_barrier(0);                                        \
    __builtin_amdgcn_s_barrier();                                             \
    __builtin_amdgcn_sched_barrier(0);                                        \
    compute(CUR);                                                             \
    __builtin_amdgcn_sched_barrier(0);                                        \
    __builtin_amdgcn_s_barrier();                                             \
  }

  for (int t = 0; t < NT; t += 2) {
    GEMM9_STEP(t,     0, R1a, R3a);
    GEMM9_STEP(t + 1, 1, R1b, R3b);
  }
#undef GEMM9_STEP

  int rbase = m0 + wr * 64 + (lane >> 4) * 4;
  int cbase = n0 + wc * 32 + (lane & 15);
#pragma unroll
  for (int mi = 0; mi < 4; ++mi) {
#pragma unroll
    for (int ni = 0; ni < 2; ++ni) {
      int col = cbase + ni * 16;
#pragma unroll
      for (int r = 0; r < 4; ++r) {
        int row = rbase + mi * 16 + r;
        float v = acc1[mi][ni][r];
        if (EPI == 0) {
          float a3 = acc3[mi][ni][r];
          float sg = v / (1.f + __expf(-v));
          Cb[(long)row * ldcb + col] = f2bf(sg * a3);
        } else if (EPI == 1) {
          C0[(long)row * ldc0 + col] = v;
        } else {
          if (row < rowlim)
            atomicAdd(&C0[(long)perm[row] * ldc0 + col], v * pwt[row]);
        }
      }
    }
  }
}

// ====== GEMM v11: ALL-bf16, BOTH operands via gload_lds, dbuf + counted vmcnt ======
// Per-iter staged: A 16KB + B 8KB(x2 dual) = 32KB, zero cvt, zero ds_write.
// vmcnt: per tile = 8 gloads (dual: A4+B2+B2) / 6 (single). After issuing t+1's
// batch, outstanding = 2 batches -> vmcnt(8/6) drains exactly tile t.
template <bool GATHER, bool DUAL, int EPI>
__global__ __launch_bounds__(256) void gemm11_kernel(
    const u16* __restrict__ A, int lda,
    const u16* __restrict__ B1, const u16* __restrict__ B3,
    int ldb, long bstride, int K,
    const int* __restrict__ tile2e, const int* __restrict__ tile2m0,
    const int* __restrict__ seg_off, const int* __restrict__ seg_cnt,
    const int* __restrict__ perm, const float* __restrict__ pwt,
    float* __restrict__ C0, int ldc0,
    u16* __restrict__ Cb, int ldcb, int Mfixed) {
  int e, m0, rowlim;
  if (tile2e) {
    e = tile2e[blockIdx.x];
    if (e < 0) return;
    m0 = tile2m0[blockIdx.x];
    rowlim = seg_off[e] + seg_cnt[e];
  } else {
    e = 0;
    m0 = blockIdx.x * 128;
    if (m0 >= Mfixed) return;
    rowlim = Mfixed;
  }
  int n0 = blockIdx.y * 64;
  const u16* Bb1 = B1 + (long)e * bstride;
  const u16* Bb3 = DUAL ? (B3 + (long)e * bstride) : nullptr;

  __shared__ u16 As[2][128 * 64];               // 32 KB
  __shared__ u16 Bs1[2][64 * 64];               // 16 KB
  __shared__ u16 Bs3[DUAL ? 2 : 1][DUAL ? 64 * 64 : 1];

  int tid = threadIdx.x;
  int lane = tid & 63;
  int wid = tid >> 6;
  int wr = wid >> 1, wc = wid & 1;

  f32x4 acc1[4][2], acc3[4][2];
#pragma unroll
  for (int mi = 0; mi < 4; ++mi)
#pragma unroll
    for (int ni = 0; ni < 2; ++ni) {
      acc1[mi][ni] = (f32x4){0.f, 0.f, 0.f, 0.f};
      acc3[mi][ni] = (f32x4){0.f, 0.f, 0.f, 0.f};
    }

  // A staging: row=tid>>3 (+32/it), chunk=tid&7; SOURCE chunk XOR'd (rule #21)
  int sr = tid >> 3;
  int scA = tid & 7;
  long abase[4];
#pragma unroll
  for (int it = 0; it < 4; ++it) {
    int row = m0 + it * 32 + sr;
    int rid = GATHER ? perm[row] : row;
    abase[it] = (long)rid * lda + ((scA ^ (sr & 7)) << 3);
  }
  // B staging (bf16): row=it*32+(tid>>3), chunk=tid&7, source chunk XOR'd
  long bbase[2];
#pragma unroll
  for (int it = 0; it < 2; ++it)
    bbase[it] = (long)(n0 + it * 32 + sr) * ldb + ((scA ^ (sr & 7)) << 3);

  auto stage = [&](int buf, int k0) {
#pragma unroll
    for (int it = 0; it < 4; ++it)
      gload_lds16(A + abase[it] + k0, &As[buf][(it * 32 + sr) * 64 + scA * 8]);
#pragma unroll
    for (int it = 0; it < 2; ++it)
      gload_lds16(Bb1 + bbase[it] + k0, &Bs1[buf][(it * 32 + sr) * 64 + scA * 8]);
    if (DUAL) {
#pragma unroll
      for (int it = 0; it < 2; ++it)
        gload_lds16(Bb3 + bbase[it] + k0, &Bs3[buf][(it * 32 + sr) * 64 + scA * 8]);
    }
  };
  auto compute = [&](int cur) {
#pragma unroll
    for (int kk = 0; kk < 64; kk += 32) {
      short8 af[4], b1f[2], b3f[2];
#pragma unroll
      for (int i = 0; i < 4; ++i) {
        int R = wr * 64 + i * 16 + (lane & 15);
        int c = (kk >> 3) + (lane >> 4);
        af[i] = *(const short8*)&As[cur][R * 64 + ((c ^ (R & 7)) << 3)];
      }
#pragma unroll
      for (int i = 0; i < 2; ++i) {
        int r = wc * 32 + i * 16 + (lane & 15);
        int cR = (kk >> 3) + (lane >> 4);
        b1f[i] = *(const short8*)&Bs1[cur][r * 64 + ((cR ^ (r & 7)) << 3)];
        if (DUAL)
          b3f[i] = *(const short8*)&Bs3[cur][r * 64 + ((cR ^ (r & 7)) << 3)];
      }
#pragma unroll
      for (int mi = 0; mi < 4; ++mi)
#pragma unroll
        for (int ni = 0; ni < 2; ++ni) {
          acc1[mi][ni] = __builtin_amdgcn_mfma_f32_16x16x32_bf16(af[mi], b1f[ni], acc1[mi][ni], 0, 0, 0);
          if (DUAL)
            acc3[mi][ni] = __builtin_amdgcn_mfma_f32_16x16x32_bf16(af[mi], b3f[ni], acc3[mi][ni], 0, 0, 0);
        }
    }
  };

  stage(0, 0);
  int NT = K >> 6;
  int cur = 0;
  for (int t = 0; t < NT; ++t) {
    int nxt = cur ^ 1;
    bool pf = (t + 1 < NT);
    if (pf) {
      stage(nxt, (t + 1) << 6);               // issue next tile first
      if (DUAL) asm volatile("s_waitcnt vmcnt(8)" ::: "memory");   // drain tile t only
      else      asm volatile("s_waitcnt vmcnt(6)" ::: "memory");
    } else {
      asm volatile("s_waitcnt vmcnt(0)" ::: "memory");
    }
    __builtin_amdgcn_sched_barrier(0);
    __builtin_amdgcn_s_barrier();             // tile t visible to all waves
    __builtin_amdgcn_sched_barrier(0);
    compute(cur);
    __builtin_amdgcn_sched_barrier(0);
    __builtin_amdgcn_s_barrier();             // all waves done with buf[cur]
    cur = nxt;
  }

  int rbase = m0 + wr * 64 + (lane >> 4) * 4;
  int cbase = n0 + wc * 32 + (lane & 15);
#pragma unroll
  for (int mi = 0; mi < 4; ++mi) {
#pragma unroll
    for (int ni = 0; ni < 2; ++ni) {
      int col = cbase + ni * 16;
#pragma unroll
      for (int r = 0; r < 4; ++r) {
        int row = rbase + mi * 16 + r;
        float v = acc1[mi][ni][r];
        if (EPI == 0) {
          float a3 = acc3[mi][ni][r];
          float sg = v / (1.f + __expf(-v));
          Cb[(long)row * ldcb + col] = f2bf(sg * a3);
        } else if (EPI == 1) {
          C0[(long)row * ldc0 + col] = v;
        } else {
          if (row < rowlim)
            atomicAdd(&C0[(long)perm[row] * ldc0 + col], v * pwt[row]);
        }
      }
    }
  }
}

extern "C" void kernel_launch(void* const* d_in, const int* in_sizes, int n_in,
                              void* d_out, int out_size, void* d_ws, size_t ws_size,
                              hipStream_t stream) {
  (void)in_sizes; (void)n_in; (void)out_size;
  const float* x   = (const float*)d_in[0];
  const float* gw  = (const float*)d_in[1];
  const float* w1  = (const float*)d_in[2];
  const float* w2  = (const float*)d_in[3];
  const float* w3  = (const float*)d_in[4];
  const float* sw1 = (const float*)d_in[5];
  const float* sw2 = (const float*)d_in[6];
  const float* sw3 = (const float*)d_in[7];
  float* out = (float*)d_out;
  char* ws = (char*)d_ws;

  int*   counts = (int*)(ws + 0);
  int*   cursor = (int*)(ws + 64);
  int*   off    = (int*)(ws + 128);
  int*   cap    = (int*)(ws + 192);
  float* ssum   = (float*)(ws + 256);
  int*   tile2e = (int*)(ws + 1024);
  int*   tile2m0= (int*)(ws + 2048);
  int*   idxb   = (int*)(ws + 4096);
  float* wtb    = (float*)(ws + 4096 + 32768);
  int*   perm   = (int*)(ws + 4096 + 65536);
  float* pwt    = (float*)(ws + 4096 + 65536 + 40960);
  u16*   xb     = (u16*)(ws + 262144);                 // 2048x2048 bf16
  double* logits = (double*)(ws + 8650752);            // 2048x16 f64
  u16*   hbuf   = (u16*)(ws + 16777216);               // 10240x1408 bf16, ends 45,613,056
  u16*   hsb    = (u16*)(ws + 45613056);               // 2048x2816 bf16, ends 57,147,392
  u16*   w1b    = (u16*)(ws + 57147392);               // 92,274,688 B, ends 149,422,080
  u16*   w3b    = (u16*)(ws + 149422080);              // 92,274,688 B, ends 241,696,768
  u16*   w2b    = w1b;                                 // reuses w1b (dead after routed1)

  const size_t NEEDED = 241696768ull;
  bool bf16w = ws_size >= NEEDED;

  hipMemsetAsync(ws, 0, 512, stream);

  if (bf16w) {
    // gate-dots || cvt(w1,w3,x -> bf16)
    prep_kernel<<<dim3(NTOK + 1536), dim3(256), 0, stream>>>(x, gw, logits, w1, w3, w1b, w3b, xb);
    topk_kernel<<<dim3(NTOK / 256), dim3(256), 0, stream>>>(logits, idxb, wtb, counts, ssum);
    setup_kernel<<<dim3(1), dim3(256), 0, stream>>>(counts, off, cap, ssum, perm, pwt,
                                                    out + AUX_IDX, tile2e, tile2m0);
    scatter_kernel<<<dim3(8), dim3(256), 0, stream>>>(idxb, wtb, off, cursor, perm, pwt);

    // routed h = silu(gather(x)@w1^T) * (gather(x)@w3^T) -> bf16   [all-bf16 gload_lds]
    gemm11_kernel<true, true, 0><<<dim3(MAXTILES, HID / 64), dim3(256), 0, stream>>>(
        xb, DIM, w1b, w3b, DIM, (long)HID * DIM, DIM, tile2e, tile2m0,
        off, counts, perm, pwt, nullptr, 0, hbuf, HID, 0);
    // shared hs (f32 B path)  ||  fused cvt w2 -> w2b (w1b region now dead)
    gemm9_kernel<false, true, 0><<<dim3(16 + 8, SHID / 64), dim3(256), 0, stream>>>(
        xb, DIM, sw1, sw3, DIM, 0, DIM, nullptr, nullptr,
        nullptr, nullptr, nullptr, nullptr, nullptr, 0, hsb, SHID, NTOK,
        w2, w2b, NW13, 16);
    // z = hs @ sw2^T (f32 B path, plain store)
    gemm9_kernel<false, false, 1><<<dim3(NTOK / 128, DIM / 64), dim3(256), 0, stream>>>(
        hsb, SHID, sw2, nullptr, SHID, 0, SHID, nullptr, nullptr,
        nullptr, nullptr, nullptr, nullptr, out, DIM, nullptr, 0, NTOK,
        nullptr, nullptr, 0, 1 << 30);
    // out += (h @ w2b^T) * pwt   [all-bf16]
    gemm11_kernel<false, false, 2><<<dim3(MAXTILES, DIM / 64), dim3(256), 0, stream>>>(
        hbuf, HID, w2b, nullptr, HID, (long)DIM * HID, HID, tile2e, tile2m0,
        off, counts, perm, pwt, out, DIM, nullptr, 0, 0);
  } else {
    // fallback = R10 plan (604 us verified)
    prep_kernel<<<dim3(NTOK), dim3(256), 0, stream>>>(x, gw, logits, w1, w3, nullptr, nullptr, nullptr);
    topk_kernel<<<dim3(NTOK / 256), dim3(256), 0, stream>>>(logits, idxb, wtb, counts, ssum);
    setup_kernel<<<dim3(1), dim3(256), 0, stream>>>(counts, off, cap, ssum, perm, pwt,
                                                    out + AUX_IDX, tile2e, tile2m0);
    scatter_kernel<<<dim3(8), dim3(256), 0, stream>>>(idxb, wtb, off, cursor, perm, pwt);
    cvtN_kernel<<<dim3(2048), dim3(256), 0, stream>>>(x, xb, (long)NTOK * DIM);
    gemm9_kernel<true, true, 0><<<dim3(MAXTILES, HID / 64), dim3(256), 0, stream>>>(
        xb, DIM, w1, w3, DIM, (long)HID * DIM, DIM, tile2e, tile2m0,
        off, counts, perm, pwt, nullptr, 0, hbuf, HID, 0, nullptr, nullptr, 0, 1 << 30);
    gemm9_kernel<false, true, 0><<<dim3(NTOK / 128, SHID / 64), dim3(256), 0, stream>>>(
        xb, DIM, sw1, sw3, DIM, 0, DIM, nullptr, nullptr,
        nullptr, nullptr, nullptr, nullptr, nullptr, 0, hsb, SHID, NTOK,
        nullptr, nullptr, 0, 1 << 30);
    gemm9_kernel<false, false, 1><<<dim3(NTOK / 128, DIM / 64), dim3(256), 0, stream>>>(
        hsb, SHID, sw2, nullptr, SHID, 0, SHID, nullptr, nullptr,
        nullptr, nullptr, nullptr, nullptr, out, DIM, nullptr, 0, NTOK,
        nullptr, nullptr, 0, 1 << 30);
    gemm9_kernel<false, false, 2><<<dim3(MAXTILES, DIM / 64), dim3(256), 0, stream>>>(
        hbuf, HID, w2, nullptr, HID, (long)DIM * HID, HID, tile2e, tile2m0,
        off, counts, perm, pwt, out, DIM, nullptr, 0, 0, nullptr, nullptr, 0, 1 << 30);
  }
}

// Round 14
// 668.585 us; speedup vs baseline: 1.7364x; 1.0868x over previous
//
#include <hip/hip_runtime.h>
#include <hip/hip_bf16.h>

typedef unsigned short u16;
typedef __attribute__((ext_vector_type(8))) short short8;
typedef __attribute__((ext_vector_type(4))) float f32x4;

#define DIM 2048
#define HID 1408
#define NE 16
#define NTOK 2048
#define TOPK_ 4
#define SHID 2816
#define CAPROWS 10240
#define MAXTILES (CAPROWS / 128)   // 80; 80 % 8 == 0 so XCD == slot % 8
#define AUX_IDX (2048 * 2048)
#define NW13 46137344L             // NE*HID*DIM elems per routed weight matrix

__device__ inline u16 f2bf(float f) {
  __bf16 h = (__bf16)f;                 // RNE hardware convert
  return __builtin_bit_cast(u16, h);
}

__device__ inline void gload_lds16(const void* g, void* l) {
  __builtin_amdgcn_global_load_lds(
      (const __attribute__((address_space(1))) unsigned int*)g,
      (__attribute__((address_space(3))) unsigned int*)l, 16, 0, 0);
}

__device__ inline void cvt8_store(const float* __restrict__ in, u16* __restrict__ out, long i) {
  float4 a = *(const float4*)(in + i);
  float4 b = *(const float4*)(in + i + 4);
  union { u16 u[8]; uint4 v; } o;
  o.u[0] = f2bf(a.x); o.u[1] = f2bf(a.y); o.u[2] = f2bf(a.z); o.u[3] = f2bf(a.w);
  o.u[4] = f2bf(b.x); o.u[5] = f2bf(b.y); o.u[6] = f2bf(b.z); o.u[7] = f2bf(b.w);
  *(uint4*)(out + i) = o.v;
}

// ---------------- gate phase 1: f64 logits, no atomics ----------------
__global__ __launch_bounds__(256) void gate_dots_kernel(
    const float* __restrict__ x, const float* __restrict__ gw,
    double* __restrict__ logits) {
  int t = blockIdx.x;
  const float* xt = x + (size_t)t * DIM;
  __shared__ double red[NE][4];
  int lane = threadIdx.x & 63, wid = threadIdx.x >> 6;
  for (int e = 0; e < NE; ++e) {
    const float* w = gw + e * DIM;
    double p = 0.0;
    for (int d = threadIdx.x; d < DIM; d += 256)
      p += (double)xt[d] * (double)w[d];
#pragma unroll
    for (int s = 32; s; s >>= 1) p += __shfl_xor(p, s);
    if (lane == 0) red[e][wid] = p;
  }
  __syncthreads();
  if (threadIdx.x < NE) {
    int e = threadIdx.x;
    logits[(size_t)t * NE + e] = red[e][0] + red[e][1] + red[e][2] + red[e][3];
  }
}

// ---------------- gate phase 2: per-token softmax + top-4 ----------------
__global__ __launch_bounds__(256) void topk_kernel(
    const double* __restrict__ logits,
    int* __restrict__ idxb, float* __restrict__ wtb,
    int* __restrict__ counts, float* __restrict__ ssum) {
  __shared__ int lcnt[NE];
  __shared__ float lsum[NE];
  if (threadIdx.x < NE) { lcnt[threadIdx.x] = 0; lsum[threadIdx.x] = 0.f; }
  __syncthreads();
  int t = blockIdx.x * 256 + threadIdx.x;
  int lane = threadIdx.x & 63;
  double sc[NE];
  double m = -1e300;
#pragma unroll
  for (int e = 0; e < NE; ++e) {
    sc[e] = logits[(size_t)t * NE + e];
    if (sc[e] > m) m = sc[e];
  }
  double s = 0.0;
#pragma unroll
  for (int e = 0; e < NE; ++e) { sc[e] = exp(sc[e] - m); s += sc[e]; }
  double inv = 1.0 / s;
#pragma unroll
  for (int e = 0; e < NE; ++e) sc[e] *= inv;
  unsigned used = 0;
  for (int k = 0; k < TOPK_; ++k) {
    int be = 0; double bv = -1.0;
#pragma unroll
    for (int e = 0; e < NE; ++e)
      if (!((used >> e) & 1u) && sc[e] > bv) { bv = sc[e]; be = e; }
    used |= 1u << be;
    idxb[t * TOPK_ + k] = be;
    wtb[t * TOPK_ + k] = (float)bv;     // ROUTE_SCALE = 1
    atomicAdd(&lcnt[be], 1);
  }
#pragma unroll
  for (int e = 0; e < NE; ++e) {
    float v = (float)sc[e];
#pragma unroll
    for (int sft = 32; sft; sft >>= 1) v += __shfl_xor(v, sft);
    if (lane == 0) atomicAdd(&lsum[e], v);
  }
  __syncthreads();
  if (threadIdx.x < NE) {
    atomicAdd(&counts[threadIdx.x], lcnt[threadIdx.x]);
    atomicAdd(&ssum[threadIdx.x], lsum[threadIdx.x]);
  }
}

// -------- segment offsets (128-padded), XCD-grouped tile map, aux loss --------
__global__ __launch_bounds__(256) void setup_kernel(
    const int* __restrict__ counts, int* __restrict__ off, int* __restrict__ cap,
    const float* __restrict__ ssum, int* __restrict__ perm, float* __restrict__ pwt,
    float* __restrict__ aux_out,
    int* __restrict__ tile2e, int* __restrict__ tile2m0) {
  for (int i = threadIdx.x; i < MAXTILES; i += 256) tile2e[i] = -1;
  __syncthreads();
  if (threadIdx.x == 0) {
    int o = 0; double aux = 0.0; int nt = 0;
    for (int e = 0; e < NE; ++e) {
      off[e] = o;
      int c = (counts[e] + 127) & ~127;
      cap[e] = c;
      for (int t = 0; t < (c >> 7); ++t) {
        int slot = (nt / 10) + (nt % 10) * 8;
        tile2e[slot] = e;
        tile2m0[slot] = o + t * 128;
        ++nt;
      }
      o += c;
      aux += ((double)counts[e] / (NTOK * TOPK_)) * ((double)ssum[e] / NTOK);
    }
    aux_out[0] = (float)(NE * aux);
  }
  for (int i = threadIdx.x; i < CAPROWS; i += 256) { perm[i] = 0; pwt[i] = 0.f; }
}

__global__ __launch_bounds__(256) void scatter_kernel(
    const int* __restrict__ idxb, const float* __restrict__ wtb,
    const int* __restrict__ off, int* __restrict__ cursor,
    int* __restrict__ perm, float* __restrict__ pwt) {
  int t = blockIdx.x * 256 + threadIdx.x;
  if (t >= NTOK) return;
  for (int k = 0; k < TOPK_; ++k) {
    int e = idxb[t * TOPK_ + k];
    int s = atomicAdd(&cursor[e], 1);
    int p = off[e] + s;
    perm[p] = t;
    pwt[p] = wtb[t * TOPK_ + k];
  }
}

// ---------------- f32 -> bf16 stream convert (x only) ----------------
__global__ __launch_bounds__(256) void cvtN_kernel(const float* __restrict__ in,
                                                   u16* __restrict__ out, long n) {
  long stride = (long)gridDim.x * 2048;
  for (long i = ((long)blockIdx.x * 256 + threadIdx.x) * 8; i < n; i += stride)
    cvt8_store(in, out, i);
}

// ====== GEMM v9 (R10, verified): f32 B reg-staged depth-2 + optional fused cvt tail ======
template <bool GATHER, bool DUAL, int EPI>
__global__ __launch_bounds__(256) void gemm9_kernel(
    const u16* __restrict__ A, int lda,
    const float* __restrict__ B1, const float* __restrict__ B3,
    int ldb, long bstride, int K,
    const int* __restrict__ tile2e, const int* __restrict__ tile2m0,
    const int* __restrict__ seg_off, const int* __restrict__ seg_cnt,
    const int* __restrict__ perm, const float* __restrict__ pwt,
    float* __restrict__ C0, int ldc0,
    u16* __restrict__ Cb, int ldcb, int Mfixed,
    const float* __restrict__ csrc, u16* __restrict__ cdst, long cn, int nxg) {
  if ((int)blockIdx.x >= nxg) {          // fused cvt tail blocks (hide w2 conversion)
    long i0 = ((long)((blockIdx.x - nxg) * gridDim.y + blockIdx.y) * 256 + threadIdx.x) * 8;
    long stride = (long)(gridDim.x - nxg) * gridDim.y * 2048;
    for (long i = i0; i < cn; i += stride) cvt8_store(csrc, cdst, i);
    return;
  }
  int e, m0, rowlim;
  if (tile2e) {
    e = tile2e[blockIdx.x];
    if (e < 0) return;
    m0 = tile2m0[blockIdx.x];
    rowlim = seg_off[e] + seg_cnt[e];
  } else {
    e = 0;
    m0 = blockIdx.x * 128;
    if (m0 >= Mfixed) return;
    rowlim = Mfixed;
  }
  int n0 = blockIdx.y * 64;
  const float* Bb1 = B1 + (long)e * bstride;
  const float* Bb3 = DUAL ? (B3 + (long)e * bstride) : nullptr;

  __shared__ u16 As[2][128 * 64];
  __shared__ u16 Bs1[64 * 64];
  __shared__ u16 Bs3[DUAL ? 64 * 64 : 1];

  int tid = threadIdx.x;
  int lane = tid & 63;
  int wid = tid >> 6;
  int wr = wid >> 1, wc = wid & 1;

  f32x4 acc1[4][2], acc3[4][2];
#pragma unroll
  for (int mi = 0; mi < 4; ++mi)
#pragma unroll
    for (int ni = 0; ni < 2; ++ni) {
      acc1[mi][ni] = (f32x4){0.f, 0.f, 0.f, 0.f};
      acc3[mi][ni] = (f32x4){0.f, 0.f, 0.f, 0.f};
    }

  int sr = tid >> 3;
  int scA = tid & 7;
  long abase[4];
#pragma unroll
  for (int it = 0; it < 4; ++it) {
    int row = m0 + it * 32 + sr;
    int rid = GATHER ? perm[row] : row;
    abase[it] = (long)rid * lda + ((scA ^ (sr & 7)) << 3);
  }
  int brr = tid >> 4;
  int gB = tid & 15;
  int wofs = (((gB >> 1) ^ (brr & 7)) << 3) + ((gB & 1) << 2);
  long bbase[4];
#pragma unroll
  for (int it = 0; it < 4; ++it)
    bbase[it] = (long)(n0 + it * 16 + brr) * ldb + gB * 4;

  float4 R1a[4], R3a[4], R1b[4], R3b[4];

  auto stageA = [&](int buf, int k0) {
#pragma unroll
    for (int it = 0; it < 4; ++it)
      gload_lds16(A + abase[it] + k0, &As[buf][(it * 32 + sr) * 64 + scA * 8]);
  };
  auto loadB = [&](float4 (&r1)[4], float4 (&r3)[4], int k0) {
#pragma unroll
    for (int it = 0; it < 4; ++it) r1[it] = *(const float4*)(Bb1 + bbase[it] + k0);
    if (DUAL) {
#pragma unroll
      for (int it = 0; it < 4; ++it) r3[it] = *(const float4*)(Bb3 + bbase[it] + k0);
    }
  };
  auto writeB = [&](float4 (&r1)[4], float4 (&r3)[4]) {
#pragma unroll
    for (int it = 0; it < 4; ++it) {
      int lo = (it * 16 + brr) * 64 + wofs;
      ushort4 o;
      o.x = f2bf(r1[it].x); o.y = f2bf(r1[it].y); o.z = f2bf(r1[it].z); o.w = f2bf(r1[it].w);
      *(ushort4*)&Bs1[lo] = o;
      if (DUAL) {
        ushort4 q;
        q.x = f2bf(r3[it].x); q.y = f2bf(r3[it].y); q.z = f2bf(r3[it].z); q.w = f2bf(r3[it].w);
        *(ushort4*)&Bs3[lo] = q;
      }
    }
  };
  auto compute = [&](int cur) {
#pragma unroll
    for (int kk = 0; kk < 64; kk += 32) {
      short8 af[4], b1f[2], b3f[2];
#pragma unroll
      for (int i = 0; i < 4; ++i) {
        int R = wr * 64 + i * 16 + (lane & 15);
        int c = (kk >> 3) + (lane >> 4);
        af[i] = *(const short8*)&As[cur][R * 64 + ((c ^ (R & 7)) << 3)];
      }
#pragma unroll
      for (int i = 0; i < 2; ++i) {
        int r = wc * 32 + i * 16 + (lane & 15);
        int cR = (kk >> 3) + (lane >> 4);
        b1f[i] = *(const short8*)&Bs1[r * 64 + ((cR ^ (r & 7)) << 3)];
        if (DUAL)
          b3f[i] = *(const short8*)&Bs3[r * 64 + ((cR ^ (r & 7)) << 3)];
      }
#pragma unroll
      for (int mi = 0; mi < 4; ++mi)
#pragma unroll
        for (int ni = 0; ni < 2; ++ni) {
          acc1[mi][ni] = __builtin_amdgcn_mfma_f32_16x16x32_bf16(af[mi], b1f[ni], acc1[mi][ni], 0, 0, 0);
          if (DUAL)
            acc3[mi][ni] = __builtin_amdgcn_mfma_f32_16x16x32_bf16(af[mi], b3f[ni], acc3[mi][ni], 0, 0, 0);
        }
    }
  };

  int NT = K >> 6;
  loadB(R1a, R3a, 0);
  stageA(0, 0);
  loadB(R1b, R3b, 64);

#define GEMM9_STEP(T, CUR, RB1, RB3)                                          \
  {                                                                           \
    int t_ = (T);                                                             \
    writeB(RB1, RB3);                                                         \
    bool hasA = (t_ + 1 < NT), hasB = (t_ + 2 < NT);                          \
    if (hasA) stageA((CUR) ^ 1, (t_ + 1) << 6);                               \
    if (hasB) loadB(RB1, RB3, (t_ + 2) << 6);                                 \
    if (hasB) {                                                               \
      if (DUAL) asm volatile("s_waitcnt vmcnt(20)" ::: "memory");             \
      else      asm volatile("s_waitcnt vmcnt(12)" ::: "memory");             \
    } else if (hasA) {                                                        \
      if (DUAL) asm volatile("s_waitcnt vmcnt(12)" ::: "memory");             \
      else      asm volatile("s_waitcnt vmcnt(8)"  ::: "memory");             \
    } else {                                                                  \
      asm volatile("s_waitcnt vmcnt(0)" ::: "memory");                        \
    }                                                                         \
    asm volatile("s_waitcnt lgkmcnt(0)" ::: "memory");                        \
    __builtin_amdgcn_sched_barrier(0);                                        \
    __builtin_amdgcn_s_barrier();                                             \
    __builtin_amdgcn_sched_barrier(0);                                        \
    compute(CUR);                                                             \
    __builtin_amdgcn_sched_barrier(0);                                        \
    __builtin_amdgcn_s_barrier();                                             \
  }

  for (int t = 0; t < NT; t += 2) {
    GEMM9_STEP(t,     0, R1a, R3a);
    GEMM9_STEP(t + 1, 1, R1b, R3b);
  }
#undef GEMM9_STEP

  int rbase = m0 + wr * 64 + (lane >> 4) * 4;
  int cbase = n0 + wc * 32 + (lane & 15);
#pragma unroll
  for (int mi = 0; mi < 4; ++mi) {
#pragma unroll
    for (int ni = 0; ni < 2; ++ni) {
      int col = cbase + ni * 16;
#pragma unroll
      for (int r = 0; r < 4; ++r) {
        int row = rbase + mi * 16 + r;
        float v = acc1[mi][ni][r];
        if (EPI == 0) {
          float a3 = acc3[mi][ni][r];
          float sg = v / (1.f + __expf(-v));
          Cb[(long)row * ldcb + col] = f2bf(sg * a3);
        } else if (EPI == 1) {
          C0[(long)row * ldc0 + col] = v;
        } else {
          if (row < rowlim)
            atomicAdd(&C0[(long)perm[row] * ldc0 + col], v * pwt[row]);
        }
      }
    }
  }
}

// ====== GEMM v11: ALL-bf16, BOTH operands via gload_lds, dbuf + counted vmcnt ======
template <bool GATHER, bool DUAL, int EPI>
__global__ __launch_bounds__(256) void gemm11_kernel(
    const u16* __restrict__ A, int lda,
    const u16* __restrict__ B1, const u16* __restrict__ B3,
    int ldb, long bstride, int K,
    const int* __restrict__ tile2e, const int* __restrict__ tile2m0,
    const int* __restrict__ seg_off, const int* __restrict__ seg_cnt,
    const int* __restrict__ perm, const float* __restrict__ pwt,
    float* __restrict__ C0, int ldc0,
    u16* __restrict__ Cb, int ldcb, int Mfixed) {
  int e, m0, rowlim;
  if (tile2e) {
    e = tile2e[blockIdx.x];
    if (e < 0) return;
    m0 = tile2m0[blockIdx.x];
    rowlim = seg_off[e] + seg_cnt[e];
  } else {
    e = 0;
    m0 = blockIdx.x * 128;
    if (m0 >= Mfixed) return;
    rowlim = Mfixed;
  }
  int n0 = blockIdx.y * 64;
  const u16* Bb1 = B1 + (long)e * bstride;
  const u16* Bb3 = DUAL ? (B3 + (long)e * bstride) : nullptr;

  __shared__ u16 As[2][128 * 64];
  __shared__ u16 Bs1[2][64 * 64];
  __shared__ u16 Bs3[DUAL ? 2 : 1][DUAL ? 64 * 64 : 1];

  int tid = threadIdx.x;
  int lane = tid & 63;
  int wid = tid >> 6;
  int wr = wid >> 1, wc = wid & 1;

  f32x4 acc1[4][2], acc3[4][2];
#pragma unroll
  for (int mi = 0; mi < 4; ++mi)
#pragma unroll
    for (int ni = 0; ni < 2; ++ni) {
      acc1[mi][ni] = (f32x4){0.f, 0.f, 0.f, 0.f};
      acc3[mi][ni] = (f32x4){0.f, 0.f, 0.f, 0.f};
    }

  int sr = tid >> 3;
  int scA = tid & 7;
  long abase[4];
#pragma unroll
  for (int it = 0; it < 4; ++it) {
    int row = m0 + it * 32 + sr;
    int rid = GATHER ? perm[row] : row;
    abase[it] = (long)rid * lda + ((scA ^ (sr & 7)) << 3);
  }
  long bbase[2];
#pragma unroll
  for (int it = 0; it < 2; ++it)
    bbase[it] = (long)(n0 + it * 32 + sr) * ldb + ((scA ^ (sr & 7)) << 3);

  auto stage = [&](int buf, int k0) {
#pragma unroll
    for (int it = 0; it < 4; ++it)
      gload_lds16(A + abase[it] + k0, &As[buf][(it * 32 + sr) * 64 + scA * 8]);
#pragma unroll
    for (int it = 0; it < 2; ++it)
      gload_lds16(Bb1 + bbase[it] + k0, &Bs1[buf][(it * 32 + sr) * 64 + scA * 8]);
    if (DUAL) {
#pragma unroll
      for (int it = 0; it < 2; ++it)
        gload_lds16(Bb3 + bbase[it] + k0, &Bs3[buf][(it * 32 + sr) * 64 + scA * 8]);
    }
  };
  auto compute = [&](int cur) {
#pragma unroll
    for (int kk = 0; kk < 64; kk += 32) {
      short8 af[4], b1f[2], b3f[2];
#pragma unroll
      for (int i = 0; i < 4; ++i) {
        int R = wr * 64 + i * 16 + (lane & 15);
        int c = (kk >> 3) + (lane >> 4);
        af[i] = *(const short8*)&As[cur][R * 64 + ((c ^ (R & 7)) << 3)];
      }
#pragma unroll
      for (int i = 0; i < 2; ++i) {
        int r = wc * 32 + i * 16 + (lane & 15);
        int cR = (kk >> 3) + (lane >> 4);
        b1f[i] = *(const short8*)&Bs1[cur][r * 64 + ((cR ^ (r & 7)) << 3)];
        if (DUAL)
          b3f[i] = *(const short8*)&Bs3[cur][r * 64 + ((cR ^ (r & 7)) << 3)];
      }
#pragma unroll
      for (int mi = 0; mi < 4; ++mi)
#pragma unroll
        for (int ni = 0; ni < 2; ++ni) {
          acc1[mi][ni] = __builtin_amdgcn_mfma_f32_16x16x32_bf16(af[mi], b1f[ni], acc1[mi][ni], 0, 0, 0);
          if (DUAL)
            acc3[mi][ni] = __builtin_amdgcn_mfma_f32_16x16x32_bf16(af[mi], b3f[ni], acc3[mi][ni], 0, 0, 0);
        }
    }
  };

  stage(0, 0);
  int NT = K >> 6;
  int cur = 0;
  for (int t = 0; t < NT; ++t) {
    int nxt = cur ^ 1;
    bool pf = (t + 1 < NT);
    if (pf) {
      stage(nxt, (t + 1) << 6);
      if (DUAL) asm volatile("s_waitcnt vmcnt(8)" ::: "memory");
      else      asm volatile("s_waitcnt vmcnt(6)" ::: "memory");
    } else {
      asm volatile("s_waitcnt vmcnt(0)" ::: "memory");
    }
    __builtin_amdgcn_sched_barrier(0);
    __builtin_amdgcn_s_barrier();
    __builtin_amdgcn_sched_barrier(0);
    compute(cur);
    __builtin_amdgcn_sched_barrier(0);
    __builtin_amdgcn_s_barrier();
    cur = nxt;
  }

  int rbase = m0 + wr * 64 + (lane >> 4) * 4;
  int cbase = n0 + wc * 32 + (lane & 15);
#pragma unroll
  for (int mi = 0; mi < 4; ++mi) {
#pragma unroll
    for (int ni = 0; ni < 2; ++ni) {
      int col = cbase + ni * 16;
#pragma unroll
      for (int r = 0; r < 4; ++r) {
        int row = rbase + mi * 16 + r;
        float v = acc1[mi][ni][r];
        if (EPI == 0) {
          float a3 = acc3[mi][ni][r];
          float sg = v / (1.f + __expf(-v));
          Cb[(long)row * ldcb + col] = f2bf(sg * a3);
        } else if (EPI == 1) {
          C0[(long)row * ldc0 + col] = v;
        } else {
          if (row < rowlim)
            atomicAdd(&C0[(long)perm[row] * ldc0 + col], v * pwt[row]);
        }
      }
    }
  }
}

extern "C" void kernel_launch(void* const* d_in, const int* in_sizes, int n_in,
                              void* d_out, int out_size, void* d_ws, size_t ws_size,
                              hipStream_t stream) {
  (void)in_sizes; (void)n_in; (void)out_size;
  const float* x   = (const float*)d_in[0];
  const float* gw  = (const float*)d_in[1];
  const float* w1  = (const float*)d_in[2];
  const float* w2  = (const float*)d_in[3];
  const float* w3  = (const float*)d_in[4];
  const float* sw1 = (const float*)d_in[5];
  const float* sw2 = (const float*)d_in[6];
  const float* sw3 = (const float*)d_in[7];
  float* out = (float*)d_out;
  char* ws = (char*)d_ws;

  int*   counts = (int*)(ws + 0);
  int*   cursor = (int*)(ws + 64);
  int*   off    = (int*)(ws + 128);
  int*   cap    = (int*)(ws + 192);
  float* ssum   = (float*)(ws + 256);
  int*   tile2e = (int*)(ws + 1024);
  int*   tile2m0= (int*)(ws + 2048);
  int*   idxb   = (int*)(ws + 4096);
  float* wtb    = (float*)(ws + 4096 + 32768);
  int*   perm   = (int*)(ws + 4096 + 65536);
  float* pwt    = (float*)(ws + 4096 + 65536 + 40960);
  u16*   xb     = (u16*)(ws + 262144);                 // 2048x2048 bf16
  double* logits = (double*)(ws + 8650752);            // 2048x16 f64
  u16*   hbuf   = (u16*)(ws + 16777216);               // 10240x1408 bf16, ends 45,613,056
  u16*   hsb    = (u16*)(ws + 45613056);               // 2048x2816 bf16, ends 57,147,392
  u16*   w2b    = (u16*)(ws + 57147392);               // 92,274,688 B, ends 149,422,080

  const size_t NEEDED = 149422080ull;
  bool havew2b = ws_size >= NEEDED;

  hipMemsetAsync(ws, 0, 512, stream);
  gate_dots_kernel<<<dim3(NTOK), dim3(256), 0, stream>>>(x, gw, logits);
  topk_kernel<<<dim3(NTOK / 256), dim3(256), 0, stream>>>(logits, idxb, wtb, counts, ssum);
  setup_kernel<<<dim3(1), dim3(256), 0, stream>>>(counts, off, cap, ssum, perm, pwt,
                                                  out + AUX_IDX, tile2e, tile2m0);
  scatter_kernel<<<dim3(8), dim3(256), 0, stream>>>(idxb, wtb, off, cursor, perm, pwt);
  cvtN_kernel<<<dim3(2048), dim3(256), 0, stream>>>(x, xb, (long)NTOK * DIM);

  if (havew2b) {
    // routed h (f32-B path)  ||  fused cvt tail: w2 -> w2b hidden under the 238us dispatch
    gemm9_kernel<true, true, 0><<<dim3(MAXTILES + 8, HID / 64), dim3(256), 0, stream>>>(
        xb, DIM, w1, w3, DIM, (long)HID * DIM, DIM, tile2e, tile2m0,
        off, counts, perm, pwt, nullptr, 0, hbuf, HID, 0,
        w2, w2b, NW13, MAXTILES);
    // shared hs = silu(x@sw1^T) * (x@sw3^T) -> bf16
    gemm9_kernel<false, true, 0><<<dim3(NTOK / 128, SHID / 64), dim3(256), 0, stream>>>(
        xb, DIM, sw1, sw3, DIM, 0, DIM, nullptr, nullptr,
        nullptr, nullptr, nullptr, nullptr, nullptr, 0, hsb, SHID, NTOK,
        nullptr, nullptr, 0, 1 << 30);
    // z = hs @ sw2^T (plain f32 store)
    gemm9_kernel<false, false, 1><<<dim3(NTOK / 128, DIM / 64), dim3(256), 0, stream>>>(
        hsb, SHID, sw2, nullptr, SHID, 0, SHID, nullptr, nullptr,
        nullptr, nullptr, nullptr, nullptr, out, DIM, nullptr, 0, NTOK,
        nullptr, nullptr, 0, 1 << 30);
    // out += (h @ w2b^T) * pwt   [ALL-bf16: halved staging + fetch]
    gemm11_kernel<false, false, 2><<<dim3(MAXTILES, DIM / 64), dim3(256), 0, stream>>>(
        hbuf, HID, w2b, nullptr, HID, (long)DIM * HID, HID, tile2e, tile2m0,
        off, counts, perm, pwt, out, DIM, nullptr, 0, 0);
  } else {
    // pure R10 plan (604 us verified)
    gemm9_kernel<true, true, 0><<<dim3(MAXTILES, HID / 64), dim3(256), 0, stream>>>(
        xb, DIM, w1, w3, DIM, (long)HID * DIM, DIM, tile2e, tile2m0,
        off, counts, perm, pwt, nullptr, 0, hbuf, HID, 0, nullptr, nullptr, 0, 1 << 30);
    gemm9_kernel<false, true, 0><<<dim3(NTOK / 128, SHID / 64), dim3(256), 0, stream>>>(
        xb, DIM, sw1, sw3, DIM, 0, DIM, nullptr, nullptr,
        nullptr, nullptr, nullptr, nullptr, nullptr, 0, hsb, SHID, NTOK,
        nullptr, nullptr, 0, 1 << 30);
    gemm9_kernel<false, false, 1><<<dim3(NTOK / 128, DIM / 64), dim3(256), 0, stream>>>(
        hsb, SHID, sw2, nullptr, SHID, 0, SHID, nullptr, nullptr,
        nullptr, nullptr, nullptr, nullptr, out, DIM, nullptr, 0, NTOK,
        nullptr, nullptr, 0, 1 << 30);
    gemm9_kernel<false, false, 2><<<dim3(MAXTILES, DIM / 64), dim3(256), 0, stream>>>(
        hbuf, HID, w2, nullptr, HID, (long)DIM * HID, HID, tile2e, tile2m0,
        off, counts, perm, pwt, out, DIM, nullptr, 0, 0, nullptr, nullptr, 0, 1 << 30);
  }
}